// Round 5
// baseline (210.264 us; speedup 1.0000x reference)
//
#include <hip/hip_runtime.h>

// Problem constants (B, C, K, H, W) = (32, 256, 64, 56, 56)
constexpr int BB  = 32;
constexpr int CC  = 256;
constexpr int HWN = 56 * 56;      // 3136 elements per channel plane
constexpr int HW4 = HWN / 4;      // 784 float4 per plane (= 3*256 + 16)

constexpr int NPLANE = 4;                  // planes per block
constexpr int GRID   = BB * CC / NPLANE;   // 2048 blocks; 8/CU, all co-resident

// Native clang vector type — required by nontemporal builtins, guarantees dwordx4.
typedef float v4f __attribute__((ext_vector_type(4)));

__device__ __forceinline__ float edac_pair(float x, float y, float lo, float hi) {
    if (x != x) x = 0.0f;            // nan_to_num
    if (y != y) y = 0.0f;
    bool mv = (x >= lo) && (x <= hi);
    bool dv = (y >= lo) && (y <= hi);
    return (mv && dv && (x != y)) ? fminf(x, y)
         : ((dv && !mv) ? y
         : (mv ? x : 0.0f));
}

__device__ __forceinline__ float edac_single(float x, float lo, float hi) {
    if (x != x) x = 0.0f;
    return ((x >= lo) && (x <= hi)) ? x : 0.0f;
}

__device__ __forceinline__ void load_plane(const float* p, int t, bool extra,
                                           v4f& x0, v4f& x1, v4f& x2, v4f& x3) {
    const v4f* vp = (const v4f*)p;
    x0 = vp[t];
    x1 = vp[t + 256];
    x2 = vp[t + 512];
    x3 = extra ? vp[t + 768] : (v4f)(0.0f);
}

__device__ __forceinline__ void store_plane(float* p, int t, bool extra,
                                            v4f r0, v4f r1, v4f r2, v4f r3) {
    v4f* vp = (v4f*)p;
    __builtin_nontemporal_store(r0, &vp[t]);
    __builtin_nontemporal_store(r1, &vp[t + 256]);
    __builtin_nontemporal_store(r2, &vp[t + 512]);
    if (extra) __builtin_nontemporal_store(r3, &vp[t + 768]);
}

__global__ __launch_bounds__(256) void edac_kernel(
    const float* __restrict__ mainp,
    const float* __restrict__ dupp,
    const float* __restrict__ lov,
    const float* __restrict__ hiv,
    const int*   __restrict__ vidx,
    float*       __restrict__ out,
    int K)
{
    const int bid = blockIdx.x;          // 0..2047
    // Swizzle: c = bid>>3 so the ~8 blocks resident on one CU (bid = i mod 256)
    // span channels {c0, c0+32, ...} -> exactly 2/8 vulnerable. The old
    // c = bid&255 mapping put SAME-channel blocks on one CU -> vulnerable CUs
    // carried 1.5x the traffic and set the kernel's tail.
    const int c   = bid >> 3;            // 0..255
    const int b0  = bid & 7;             // batches b0, b0+8, b0+16, b0+24
    const int t   = threadIdx.x;

    // One vidx search per block (all 4 planes share the channel).
    __shared__ int sk;
    if (t == 0) sk = -1;
    __syncthreads();
    if (t < K && vidx[t] == c) sk = t;
    __syncthreads();
    const int k = sk;

    const float lo = lov[c];
    const float hi = hiv[c];
    const bool extra = (t < HW4 - 3 * 256);   // t < 16

    const size_t step = (size_t)8 * CC * HWN;            // batch stride 8 in main/out
    const float* mb = mainp + ((size_t)b0 * CC + c) * HWN;
    float*       ob = out   + ((size_t)b0 * CC + c) * HWN;

    if (k >= 0) {
        const size_t dstep = (size_t)8 * K * HWN;        // batch stride 8 in dup
        const float* db = dupp + ((size_t)b0 * K + k) * HWN;

        v4f a0, a1, a2, a3, da0, da1, da2, da3;
        load_plane(mb, t, extra, a0, a1, a2, a3);
        load_plane(db, t, extra, da0, da1, da2, da3);

        #pragma unroll
        for (int i = 0; i < NPLANE; ++i) {
            v4f n0, n1, n2, n3, nd0, nd1, nd2, nd3;
            if (i + 1 < NPLANE) {
                load_plane(mb + (size_t)(i + 1) * step,  t, extra, n0, n1, n2, n3);
                load_plane(db + (size_t)(i + 1) * dstep, t, extra, nd0, nd1, nd2, nd3);
            }
            v4f r0, r1, r2, r3;
            #pragma unroll
            for (int e = 0; e < 4; ++e) {
                r0[e] = edac_pair(a0[e], da0[e], lo, hi);
                r1[e] = edac_pair(a1[e], da1[e], lo, hi);
                r2[e] = edac_pair(a2[e], da2[e], lo, hi);
                r3[e] = edac_pair(a3[e], da3[e], lo, hi);
            }
            store_plane(ob + (size_t)i * step, t, extra, r0, r1, r2, r3);
            a0 = n0; a1 = n1; a2 = n2; a3 = n3;
            da0 = nd0; da1 = nd1; da2 = nd2; da3 = nd3;
        }
    } else {
        v4f a0, a1, a2, a3;
        load_plane(mb, t, extra, a0, a1, a2, a3);

        #pragma unroll
        for (int i = 0; i < NPLANE; ++i) {
            v4f n0, n1, n2, n3;
            if (i + 1 < NPLANE) {
                load_plane(mb + (size_t)(i + 1) * step, t, extra, n0, n1, n2, n3);
            }
            v4f r0, r1, r2, r3;
            #pragma unroll
            for (int e = 0; e < 4; ++e) {
                r0[e] = edac_single(a0[e], lo, hi);
                r1[e] = edac_single(a1[e], lo, hi);
                r2[e] = edac_single(a2[e], lo, hi);
                r3[e] = edac_single(a3[e], lo, hi);
            }
            store_plane(ob + (size_t)i * step, t, extra, r0, r1, r2, r3);
            a0 = n0; a1 = n1; a2 = n2; a3 = n3;
        }
    }
}

extern "C" void kernel_launch(void* const* d_in, const int* in_sizes, int n_in,
                              void* d_out, int out_size, void* d_ws, size_t ws_size,
                              hipStream_t stream) {
    const float* mainp = (const float*)d_in[0];
    const float* dupp  = (const float*)d_in[1];
    const float* lov   = (const float*)d_in[2];
    const float* hiv   = (const float*)d_in[3];
    const int*   vidx  = (const int*)d_in[4];
    const int    K     = in_sizes[4];

    hipLaunchKernelGGL(edac_kernel, dim3(GRID), dim3(256), 0, stream,
                       mainp, dupp, lov, hiv, vidx, (float*)d_out, K);
}

// Round 6
// 199.060 us; speedup vs baseline: 1.0563x; 1.0563x over previous
//
#include <hip/hip_runtime.h>

// Problem constants (B, C, K, H, W) = (32, 256, 64, 56, 56)
constexpr int BB   = 32;
constexpr int CC   = 256;
constexpr int HWN  = 56 * 56;                       // 3136 floats per plane
constexpr int PL4  = HWN / 4;                       // 784 float4 per plane
constexpr int N4   = BB * CC * PL4;                 // 6,422,528 float4 total
constexpr int GRID = 3136;                          // 3136 blk * 256 thr * 8 f4 = N4 exactly
constexpr int TT   = GRID * 256;                    // total threads = 802,816

// floor(y/49) for y < 2^19 via magic multiply: m*49 = 2^31 + 5, 5*y_max << 2^31.
constexpr unsigned long long MAGIC49 = 43826197ull;

typedef float v4f __attribute__((ext_vector_type(4)));

__device__ __forceinline__ float edac_pair(float x, float y, float lo, float hi) {
    if (x != x) x = 0.0f;            // nan_to_num
    if (y != y) y = 0.0f;
    bool mv = (x >= lo) && (x <= hi);
    bool dv = (y >= lo) && (y <= hi);
    return (mv && dv && (x != y)) ? fminf(x, y)
         : ((dv && !mv) ? y
         : (mv ? x : 0.0f));
}

__device__ __forceinline__ float edac_single(float x, float lo, float hi) {
    if (x != x) x = 0.0f;
    return ((x >= lo) && (x <= hi)) ? x : 0.0f;
}

__global__ __launch_bounds__(256) void edac_flat(
    const float* __restrict__ mainp,
    const float* __restrict__ dupp,
    const float* __restrict__ lov,
    const float* __restrict__ hiv,
    const int*   __restrict__ vidx,
    float*       __restrict__ out,
    int K)
{
    __shared__ float s_lo[CC];
    __shared__ float s_hi[CC];
    __shared__ int   s_inv[CC];

    const int t = threadIdx.x;
    s_lo[t]  = lov[t];
    s_hi[t]  = hiv[t];
    s_inv[t] = -1;
    __syncthreads();
    if (t < K) s_inv[vidx[t]] = t;
    __syncthreads();

    const v4f* m4 = (const v4f*)mainp;
    const v4f* d4 = (const v4f*)dupp;
    v4f*       o4 = (v4f*)out;

    const int j0 = blockIdx.x * 256 + t;

    // 8 float4 per thread, two unrolled groups of 4. Grid-stride spacing TT
    // keeps every wave's 64 lanes on 64 consecutive float4s (256 consecutive
    // floats) -> fully coalesced, and within <=2 channels (mostly uniform).
    #pragma unroll
    for (int g = 0; g < 2; ++g) {
        int j[4];
        v4f m[4];
        #pragma unroll
        for (int u = 0; u < 4; ++u) {
            j[u] = j0 + (g * 4 + u) * TT;
            m[u] = __builtin_nontemporal_load(&m4[j[u]]);
        }

        int   k[4];
        float lo[4], hi[4];
        v4f   d[4];
        #pragma unroll
        for (int u = 0; u < 4; ++u) {
            const unsigned y  = ((unsigned)j[u]) >> 4;
            const int plane   = (int)((y * MAGIC49) >> 31);   // j/784
            const int c       = plane & (CC - 1);
            lo[u] = s_lo[c];
            hi[u] = s_hi[c];
            k[u]  = s_inv[c];
            if (k[u] >= 0) {
                const int b   = plane >> 8;                   // / CC
                const int hw4 = j[u] - plane * PL4;
                d[u] = __builtin_nontemporal_load(&d4[((size_t)b * K + k[u]) * PL4 + hw4]);
            } else {
                d[u] = (v4f)(0.0f);
            }
        }

        #pragma unroll
        for (int u = 0; u < 4; ++u) {
            v4f r;
            if (k[u] >= 0) {
                #pragma unroll
                for (int e = 0; e < 4; ++e)
                    r[e] = edac_pair(m[u][e], d[u][e], lo[u], hi[u]);
            } else {
                #pragma unroll
                for (int e = 0; e < 4; ++e)
                    r[e] = edac_single(m[u][e], lo[u], hi[u]);
            }
            __builtin_nontemporal_store(r, &o4[j[u]]);
        }
    }
}

extern "C" void kernel_launch(void* const* d_in, const int* in_sizes, int n_in,
                              void* d_out, int out_size, void* d_ws, size_t ws_size,
                              hipStream_t stream) {
    const float* mainp = (const float*)d_in[0];
    const float* dupp  = (const float*)d_in[1];
    const float* lov   = (const float*)d_in[2];
    const float* hiv   = (const float*)d_in[3];
    const int*   vidx  = (const int*)d_in[4];
    const int    K     = in_sizes[4];

    hipLaunchKernelGGL(edac_flat, dim3(GRID), dim3(256), 0, stream,
                       mainp, dupp, lov, hiv, vidx, (float*)d_out, K);
}